// Round 14
// baseline (421.280 us; speedup 1.0000x reference)
//
#include <hip/hip_runtime.h>
#include <hip/hip_bf16.h>

#define N_NODES 100000
#define F_IN    256
#define H_DIM   128
#define C_CLS   16
#define NSHARD  8
#define SHARD_W ((N_NODES + NSHARD - 1) / NSHARD)   // 12500
#define MAXDEG  64                                  // ELL row width; deg~Poisson(16)
#define ZB      98                                  // cnt-zeroing blocks

typedef __attribute__((ext_vector_type(8))) short  short8;
typedef __attribute__((ext_vector_type(4))) float  float4v;
typedef __attribute__((ext_vector_type(4))) unsigned short ushort4v;

__device__ __forceinline__ float b2f(ushort u) {
    union { unsigned int i; float f; } v;
    v.i = ((unsigned int)u) << 16;
    return v.f;
}

__device__ __forceinline__ ushort f2b(float f) {
    unsigned int x = __float_as_uint(f);
    unsigned int r = (x + 0x7FFFu + ((x >> 16) & 1u)) >> 16;   // RNE
    return (ushort)r;
}

__device__ __forceinline__ float ldsel(const void* p, int i, int f32f) {
    return f32f ? ((const float*)p)[i] : b2f(((const ushort*)p)[i]);
}

// ------------------------------------------------------------------ sniff ---
__global__ __launch_bounds__(64) void sniff(const ushort* __restrict__ x,
                                            const int* __restrict__ ei,
                                            int* __restrict__ flags) {
    int lane = threadIdx.x;
    int cnt_bf = 0;
#pragma unroll
    for (int j = 0; j < 4; ++j) {
        ushort u = x[lane * 4 + j];
        int e = (u >> 7) & 0xFF;
        if ((e >= 100 && e <= 140) || (u & 0x7FFF) == 0) cnt_bf++;
    }
    int zodd = (ei[2 * lane + 1] == 0) ? 1 : 0;
#pragma unroll
    for (int off = 32; off >= 1; off >>= 1) {
        cnt_bf += __shfl_xor(cnt_bf, off, 64);
        zodd   += __shfl_xor(zodd,   off, 64);
    }
    if (lane == 0) {
        flags[0] = (cnt_bf < 230) ? 1 : 0;   // f32 inputs
        flags[1] = (zodd  >= 32) ? 1 : 0;    // int64 indices
    }
}

// -------- merged param prep: wtg = W^T + bayes weights + zero cnt/ocnt ------
__global__ __launch_bounds__(256) void prep_params(const int* __restrict__ flags,
                                                   const void* __restrict__ W_any,
                                                   ushort* __restrict__ wtg,
                                                   const void* __restrict__ w_mu,
                                                   const void* __restrict__ w_ls,
                                                   const void* __restrict__ eps_w,
                                                   const void* __restrict__ b_mu,
                                                   const void* __restrict__ b_ls,
                                                   const void* __restrict__ eps_b,
                                                   const void* __restrict__ gcn_b,
                                                   ushort* __restrict__ whi,
                                                   ushort* __restrict__ wlo,
                                                   float* __restrict__ bias16,
                                                   float* __restrict__ gcnb_f,
                                                   int* __restrict__ cnt,
                                                   int* __restrict__ ocnt) {
    const int f32f = flags[0];
    const int t = threadIdx.x;
    if (blockIdx.x < H_DIM) {
        const int n = blockIdx.x;      // 0..127
        float v = f32f ? ((const float*)W_any)[t * H_DIM + n]
                       : b2f(((const ushort*)W_any)[t * H_DIM + n]);
        wtg[n * F_IN + t] = f2b(v);
        return;
    }
    if (blockIdx.x > H_DIM) {
        int idx4 = (blockIdx.x - H_DIM - 1) * 256 + t;   // int4 index
        if (idx4 < N_NODES / 4) ((int4*)cnt)[idx4] = make_int4(0, 0, 0, 0);
        return;
    }
    if (t == 0) *ocnt = 0;
#pragma unroll
    for (int i = t; i < C_CLS * H_DIM; i += 256) {
        float v = ldsel(w_mu, i, f32f) + __expf(ldsel(w_ls, i, f32f)) * ldsel(eps_w, i, f32f);
        ushort h = f2b(v);
        whi[i] = h;
        wlo[i] = f2b(v - b2f(h));     // residual: recovers ~16-bit mantissa
    }
    if (t < C_CLS)
        bias16[t] = ldsel(b_mu, t, f32f) + __expf(ldsel(b_ls, t, f32f)) * ldsel(eps_b, t, f32f);
    if (t < H_DIM)
        gcnb_f[t] = ldsel(gcn_b, t, f32f);
}

// ---------------- ONE-PASS count + rank + ELL scatter (XCD-sharded) ---------
__global__ __launch_bounds__(256) void ell_scatter(const int* __restrict__ flags,
                                                   const int* __restrict__ ei,
                                                   int* __restrict__ cnt,
                                                   int* __restrict__ ell,
                                                   int2* __restrict__ ovf,
                                                   int* __restrict__ ocnt, int E) {
    const int shard = blockIdx.x & (NSHARD - 1);
    const int jb    = blockIdx.x >> 3;
    const int nb    = gridDim.x >> 3;
    const int lo = shard * SHARD_W;
    const int hi = lo + SHARD_W;                 // N divides evenly
    const int i64 = flags[1];
    for (long e = (long)jb * 256 + threadIdx.x; e < E; e += (long)nb * 256) {
        int d = i64 ? ei[2L * E + 2L * e] : ei[(long)E + e];
        if (d >= lo && d < hi) {
            int s = i64 ? ei[2L * e] : ei[e];
            int rk = atomicAdd(&cnt[d], 1);
            if (rk < MAXDEG) ell[(long)d * MAXDEG + rk] = s;
            else { int oi = atomicAdd(ocnt, 1); ovf[oi] = make_int2(s, d); }
        }
    }
}

// ------------------------------- h' = (x @ W) * rsqrt(deg+1) ----------------
__global__ __launch_bounds__(256) void gemm_xw(const int* __restrict__ flags,
                                               const void* __restrict__ x_any,
                                               const ushort* __restrict__ wtg,
                                               const int* __restrict__ cnt,
                                               ushort* __restrict__ hout) {
    __shared__ __align__(16) ushort wt[128 * 128];      // 32768 B
    const int f32f = flags[0];

    const int tid  = threadIdx.x;
    const int lane = tid & 63;
    const int quad = lane >> 4;
    const int lm   = lane & 15;
    const int wave = tid >> 6;

    const int rbase = blockIdx.x * 128 + wave * 32;
    int arow0 = rbase + lm;
    int arow1 = rbase + 16 + lm;
    if (arow0 >= N_NODES) arow0 = N_NODES - 1;    // clamp; store is guarded
    if (arow1 >= N_NODES) arow1 = N_NODES - 1;
    const float*  xrf0 = (const float*) x_any + (size_t)arow0 * F_IN;
    const float*  xrf1 = (const float*) x_any + (size_t)arow1 * F_IN;
    const ushort* xrb0 = (const ushort*)x_any + (size_t)arow0 * F_IN;
    const ushort* xrb1 = (const ushort*)x_any + (size_t)arow1 * F_IN;

    float4v acc0[8], acc1[8];
#pragma unroll
    for (int c = 0; c < 8; ++c) {
        acc0[c] = (float4v){0.f, 0.f, 0.f, 0.f};
        acc1[c] = (float4v){0.f, 0.f, 0.f, 0.f};
    }

    for (int hh = 0; hh < 2; ++hh) {
        if (hh) __syncthreads();
#pragma unroll
        for (int it = 0; it < 8; ++it) {
            int flat = (it * 256 + tid) * 8;       // ushort idx, 0..16376
            int col  = flat >> 7;
            int kloc = flat & 127;
            short8 v = *(const short8*)(wtg + col * F_IN + hh * 128 + kloc);
            int dst = ((col << 7) | kloc) ^ ((col & 7) << 3);
            *(short8*)(wt + dst) = v;
        }
        __syncthreads();
#pragma unroll
        for (int s = 0; s < 4; ++s) {
            int klocal = s * 32 + quad * 8;
            short8 afrag0, afrag1;
            if (f32f) {
                const float* p0 = xrf0 + hh * 128 + klocal;
                const float* p1 = xrf1 + hh * 128 + klocal;
                float4 u0 = *(const float4*)p0;
                float4 u1 = *(const float4*)(p0 + 4);
                float4 u2 = *(const float4*)p1;
                float4 u3 = *(const float4*)(p1 + 4);
                afrag0[0] = (short)f2b(u0.x); afrag0[1] = (short)f2b(u0.y);
                afrag0[2] = (short)f2b(u0.z); afrag0[3] = (short)f2b(u0.w);
                afrag0[4] = (short)f2b(u1.x); afrag0[5] = (short)f2b(u1.y);
                afrag0[6] = (short)f2b(u1.z); afrag0[7] = (short)f2b(u1.w);
                afrag1[0] = (short)f2b(u2.x); afrag1[1] = (short)f2b(u2.y);
                afrag1[2] = (short)f2b(u2.z); afrag1[3] = (short)f2b(u2.w);
                afrag1[4] = (short)f2b(u3.x); afrag1[5] = (short)f2b(u3.y);
                afrag1[6] = (short)f2b(u3.z); afrag1[7] = (short)f2b(u3.w);
            } else {
                afrag0 = *(const short8*)(xrb0 + hh * 128 + klocal);
                afrag1 = *(const short8*)(xrb1 + hh * 128 + klocal);
            }
#pragma unroll
            for (int c = 0; c < 8; ++c) {
                int colr = c * 16 + lm;
                int src = ((colr << 7) | klocal) ^ ((lm & 7) << 3);
                short8 bfrag = *(const short8*)(wt + src);
                acc0[c] = __builtin_amdgcn_mfma_f32_16x16x32_bf16(afrag0, bfrag, acc0[c], 0, 0, 0);
                acc1[c] = __builtin_amdgcn_mfma_f32_16x16x32_bf16(afrag1, bfrag, acc1[c], 0, 0, 0);
            }
        }
    }
    // D[row=quad*4+r][col=lane&15]; scale rows by rsqrt(deg+1) before rounding
    float dv0[4], dv1[4];
#pragma unroll
    for (int r = 0; r < 4; ++r) {
        int n0 = rbase + quad * 4 + r;
        int n1 = rbase + 16 + quad * 4 + r;
        dv0[r] = (n0 < N_NODES) ? rsqrtf((float)(cnt[n0] + 1)) : 0.f;
        dv1[r] = (n1 < N_NODES) ? rsqrtf((float)(cnt[n1] + 1)) : 0.f;
    }
#pragma unroll
    for (int c = 0; c < 8; ++c) {
        int col = c * 16 + lm;
#pragma unroll
        for (int r = 0; r < 4; ++r) {
            int n0 = rbase + quad * 4 + r;
            int n1 = rbase + 16 + quad * 4 + r;
            if (n0 < N_NODES) hout[(size_t)n0 * H_DIM + col] = f2b(acc0[c][r] * dv0[r]);
            if (n1 < N_NODES) hout[(size_t)n1 * H_DIM + col] = f2b(acc1[c][r] * dv1[r]);
        }
    }
}

// ------- FUSED: ELL gather + bias/relu -> LDS -> bayes linear + lsm ---------
// Round-14 restructure: nodes processed in PAIRS per wave. Both nodes' ELL
// batches load together (32 row-fetches in flight vs 16; scalar index loads
// batched for two rows), then a separate accumulate loop with 4 independent
// chains (axA/ayA/axB/ayB). Masked slots skip the load (u=0 adds 0.0).
// Doubles memory-level parallelism if the gather is latency-bound.
__global__ __launch_bounds__(256) void gather_final(const int* __restrict__ flags,
                                                    const int* __restrict__ cnt,
                                                    const int* __restrict__ ell,
                                                    const int2* __restrict__ ovf,
                                                    const int* __restrict__ ocnt,
                                                    const ushort* __restrict__ hb,
                                                    const float* __restrict__ gcnb_f,
                                                    const ushort* __restrict__ whi,
                                                    const ushort* __restrict__ wlo,
                                                    const float* __restrict__ bias16,
                                                    void* __restrict__ out) {
    __shared__ __align__(16) ushort alds[16][136];   // 4352 B, pad 8
    const int f32f = flags[0];
    const int lane = threadIdx.x & 63;
    const int wave = threadIdx.x >> 6;
    const int n0 = blockIdx.x * 16;                  // 16 | N_NODES

    // ------------- gather phase: 2 node-pairs per wave, paired loads --------
    for (int rp = 0; rp < 2; ++rp) {
        const int nodeA = n0 + wave * 4 + rp * 2;
        const int nodeB = nodeA + 1;
        const int degtA = __builtin_amdgcn_readfirstlane(cnt[nodeA]);
        const int degtB = __builtin_amdgcn_readfirstlane(cnt[nodeB]);
        const int degA = degtA < MAXDEG ? degtA : MAXDEG;
        const int degB = degtB < MAXDEG ? degtB : MAXDEG;
        const int* ppA = ell + (long)nodeA * MAXDEG;
        const int* ppB = ell + (long)nodeB * MAXDEG;

        float axA = 0.f, ayA = 0.f, axB = 0.f, ayB = 0.f;
        const int dmax = degA > degB ? degA : degB;
        for (int base = 0; base < dmax; base += 16) {
            const int nbA = degA - base;            // uniform, may be <=0
            const int nbB = degB - base;
            uint uA[16], uB[16];
#pragma unroll
            for (int k = 0; k < 16; ++k) {
                uA[k] = 0u; uB[k] = 0u;
                if (k < nbA)
                    uA[k] = *((const uint*)(hb + (size_t)ppA[base + k] * H_DIM) + lane);
                if (k < nbB)
                    uB[k] = *((const uint*)(hb + (size_t)ppB[base + k] * H_DIM) + lane);
            }
#pragma unroll
            for (int k = 0; k < 16; ++k) {
                axA += __uint_as_float(uA[k] << 16);
                ayA += __uint_as_float(uA[k] & 0xFFFF0000u);
                axB += __uint_as_float(uB[k] << 16);
                ayB += __uint_as_float(uB[k] & 0xFFFF0000u);
            }
        }
        if (degtA > MAXDEG) {                        // rare: scan overflow list
            const int no = __builtin_amdgcn_readfirstlane(*ocnt);
            for (int j = 0; j < no; ++j) {
                int2 o = ovf[j];
                if (o.y == nodeA) {
                    uint u = *((const uint*)(hb + (size_t)o.x * H_DIM) + lane);
                    axA += __uint_as_float(u << 16);
                    ayA += __uint_as_float(u & 0xFFFF0000u);
                }
            }
        }
        if (degtB > MAXDEG) {
            const int no = __builtin_amdgcn_readfirstlane(*ocnt);
            for (int j = 0; j < no; ++j) {
                int2 o = ovf[j];
                if (o.y == nodeB) {
                    uint u = *((const uint*)(hb + (size_t)o.x * H_DIM) + lane);
                    axB += __uint_as_float(u << 16);
                    ayB += __uint_as_float(u & 0xFFFF0000u);
                }
            }
        }

        const float2 gb = *(const float2*)(gcnb_f + 2 * lane);
        {
            const float dd = rsqrtf((float)(degtA + 1));
            uint us = *((const uint*)(hb + (size_t)nodeA * H_DIM) + lane);
            float x0 = (axA + __uint_as_float(us << 16))          * dd + gb.x;
            float y0 = (ayA + __uint_as_float(us & 0xFFFF0000u))  * dd + gb.y;
            x0 = fmaxf(x0, 0.f); y0 = fmaxf(y0, 0.f);
            *((uint*)&alds[wave * 4 + rp * 2][2 * lane]) =
                (uint)f2b(x0) | ((uint)f2b(y0) << 16);
        }
        {
            const float dd = rsqrtf((float)(degtB + 1));
            uint us = *((const uint*)(hb + (size_t)nodeB * H_DIM) + lane);
            float x0 = (axB + __uint_as_float(us << 16))          * dd + gb.x;
            float y0 = (ayB + __uint_as_float(us & 0xFFFF0000u))  * dd + gb.y;
            x0 = fmaxf(x0, 0.f); y0 = fmaxf(y0, 0.f);
            *((uint*)&alds[wave * 4 + rp * 2 + 1][2 * lane]) =
                (uint)f2b(x0) | ((uint)f2b(y0) << 16);
        }
    }
    __syncthreads();
    if (wave != 0) return;

    // ---------------- final phase (wave 0): logits + log_softmax ------------
    const int lm = lane & 15, quad = lane >> 4;
    const ushort* bh = whi + lm * H_DIM + quad * 8;
    const ushort* bl = wlo + lm * H_DIM + quad * 8;

    float4v acc = (float4v){0.f, 0.f, 0.f, 0.f};
#pragma unroll
    for (int s = 0; s < 4; ++s) {
        short8 af = *(const short8*)&alds[lm][quad * 8 + s * 32];
        short8 b0 = *(const short8*)(bh + s * 32);
        short8 b1 = *(const short8*)(bl + s * 32);
        acc = __builtin_amdgcn_mfma_f32_16x16x32_bf16(af, b0, acc, 0, 0, 0);
        acc = __builtin_amdgcn_mfma_f32_16x16x32_bf16(af, b1, acc, 0, 0, 0);
    }

    const float bias = bias16[lm];
    float p[4], m[4], ss[4];
#pragma unroll
    for (int r = 0; r < 4; ++r) { p[r] = acc[r] + bias; m[r] = p[r]; }
#pragma unroll
    for (int off = 1; off < 16; off <<= 1)
#pragma unroll
        for (int r = 0; r < 4; ++r) m[r] = fmaxf(m[r], __shfl_xor(m[r], off, 64));
#pragma unroll
    for (int r = 0; r < 4; ++r) ss[r] = __expf(p[r] - m[r]);
#pragma unroll
    for (int off = 1; off < 16; off <<= 1)
#pragma unroll
        for (int r = 0; r < 4; ++r) ss[r] += __shfl_xor(ss[r], off, 64);

    if (f32f) {
        float* op = (float*)out;
#pragma unroll
        for (int r = 0; r < 4; ++r)
            op[(size_t)(n0 + quad * 4 + r) * C_CLS + lm] = p[r] - m[r] - __logf(ss[r]);
    } else {
        ushort* op = (ushort*)out;
#pragma unroll
        for (int r = 0; r < 4; ++r)
            op[(size_t)(n0 + quad * 4 + r) * C_CLS + lm] = f2b(p[r] - m[r] - __logf(ss[r]));
    }
}

// ---------------------------------------------------------------------------
extern "C" void kernel_launch(void* const* d_in, const int* in_sizes, int n_in,
                              void* d_out, int out_size, void* d_ws, size_t ws_size,
                              hipStream_t stream) {
    const int E = in_sizes[1] / 2;

    char* wp = (char*)d_ws;
    auto alloc = [&](size_t bytes) -> char* {
        char* p = wp; wp += (bytes + 511) & ~(size_t)511; return p;
    };
    int*    flags  = (int*)   alloc(64);
    ushort* hb     = (ushort*)alloc((size_t)N_NODES * H_DIM * 2);   // bf16 h*dis
    int*    cnt    = (int*)   alloc((size_t)N_NODES * 4);
    int*    ell    = (int*)   alloc((size_t)N_NODES * MAXDEG * 4);  // 25.6 MB
    int2*   ovf    = (int2*)  alloc((size_t)E * 8);                 // overflow (rare)
    int*    ocnt   = (int*)   alloc(64);
    ushort* wtg    = (ushort*)alloc((size_t)H_DIM * F_IN * 2);      // W^T bf16
    ushort* whi    = (ushort*)alloc((size_t)C_CLS * H_DIM * 2);
    ushort* wlo    = (ushort*)alloc((size_t)C_CLS * H_DIM * 2);
    float*  bias16 = (float*) alloc((size_t)C_CLS * 4);
    float*  gcnb_f = (float*) alloc((size_t)H_DIM * 4);

    sniff<<<1, 64, 0, stream>>>((const ushort*)d_in[0], (const int*)d_in[1], flags);
    prep_params<<<H_DIM + 1 + ZB, 256, 0, stream>>>(flags, d_in[2], wtg,
                                  d_in[4], d_in[5], d_in[8],
                                  d_in[6], d_in[7], d_in[9], d_in[3],
                                  whi, wlo, bias16, gcnb_f, cnt, ocnt);
    ell_scatter<<<2048, 256, 0, stream>>>(flags, (const int*)d_in[1], cnt, ell, ovf, ocnt, E);
    gemm_xw<<<(N_NODES + 127) / 128, 256, 0, stream>>>(flags, d_in[0], wtg, cnt, hb);
    gather_final<<<N_NODES / 16, 256, 0, stream>>>(flags, cnt, ell, ovf, ocnt, hb,
                                                   gcnb_f, whi, wlo, bias16, (void*)d_out);
}

// Round 15
// 373.463 us; speedup vs baseline: 1.1280x; 1.1280x over previous
//
#include <hip/hip_runtime.h>
#include <hip/hip_bf16.h>

#define N_NODES 100000
#define F_IN    256
#define H_DIM   128
#define C_CLS   16
#define NSHARD  8
#define SHARD_W ((N_NODES + NSHARD - 1) / NSHARD)   // 12500
#define MAXDEG  64                                  // ELL row width; deg~Poisson(16)
#define ZB      98                                  // cnt-zeroing blocks

typedef __attribute__((ext_vector_type(8))) short  short8;
typedef __attribute__((ext_vector_type(4))) float  float4v;
typedef __attribute__((ext_vector_type(4))) unsigned short ushort4v;

__device__ __forceinline__ float b2f(ushort u) {
    union { unsigned int i; float f; } v;
    v.i = ((unsigned int)u) << 16;
    return v.f;
}

__device__ __forceinline__ ushort f2b(float f) {
    unsigned int x = __float_as_uint(f);
    unsigned int r = (x + 0x7FFFu + ((x >> 16) & 1u)) >> 16;   // RNE
    return (ushort)r;
}

__device__ __forceinline__ float ldsel(const void* p, int i, int f32f) {
    return f32f ? ((const float*)p)[i] : b2f(((const ushort*)p)[i]);
}

// ------------------------------------------------------------------ sniff ---
__global__ __launch_bounds__(64) void sniff(const ushort* __restrict__ x,
                                            const int* __restrict__ ei,
                                            int* __restrict__ flags) {
    int lane = threadIdx.x;
    int cnt_bf = 0;
#pragma unroll
    for (int j = 0; j < 4; ++j) {
        ushort u = x[lane * 4 + j];
        int e = (u >> 7) & 0xFF;
        if ((e >= 100 && e <= 140) || (u & 0x7FFF) == 0) cnt_bf++;
    }
    int zodd = (ei[2 * lane + 1] == 0) ? 1 : 0;
#pragma unroll
    for (int off = 32; off >= 1; off >>= 1) {
        cnt_bf += __shfl_xor(cnt_bf, off, 64);
        zodd   += __shfl_xor(zodd,   off, 64);
    }
    if (lane == 0) {
        flags[0] = (cnt_bf < 230) ? 1 : 0;   // f32 inputs
        flags[1] = (zodd  >= 32) ? 1 : 0;    // int64 indices
    }
}

// -------- merged param prep: wtg = W^T + bayes weights + zero cnt/ocnt ------
__global__ __launch_bounds__(256) void prep_params(const int* __restrict__ flags,
                                                   const void* __restrict__ W_any,
                                                   ushort* __restrict__ wtg,
                                                   const void* __restrict__ w_mu,
                                                   const void* __restrict__ w_ls,
                                                   const void* __restrict__ eps_w,
                                                   const void* __restrict__ b_mu,
                                                   const void* __restrict__ b_ls,
                                                   const void* __restrict__ eps_b,
                                                   const void* __restrict__ gcn_b,
                                                   ushort* __restrict__ whi,
                                                   ushort* __restrict__ wlo,
                                                   float* __restrict__ bias16,
                                                   float* __restrict__ gcnb_f,
                                                   int* __restrict__ cnt,
                                                   int* __restrict__ ocnt) {
    const int f32f = flags[0];
    const int t = threadIdx.x;
    if (blockIdx.x < H_DIM) {
        const int n = blockIdx.x;      // 0..127
        float v = f32f ? ((const float*)W_any)[t * H_DIM + n]
                       : b2f(((const ushort*)W_any)[t * H_DIM + n]);
        wtg[n * F_IN + t] = f2b(v);
        return;
    }
    if (blockIdx.x > H_DIM) {
        int idx4 = (blockIdx.x - H_DIM - 1) * 256 + t;   // int4 index
        if (idx4 < N_NODES / 4) ((int4*)cnt)[idx4] = make_int4(0, 0, 0, 0);
        return;
    }
    if (t == 0) *ocnt = 0;
#pragma unroll
    for (int i = t; i < C_CLS * H_DIM; i += 256) {
        float v = ldsel(w_mu, i, f32f) + __expf(ldsel(w_ls, i, f32f)) * ldsel(eps_w, i, f32f);
        ushort h = f2b(v);
        whi[i] = h;
        wlo[i] = f2b(v - b2f(h));     // residual: recovers ~16-bit mantissa
    }
    if (t < C_CLS)
        bias16[t] = ldsel(b_mu, t, f32f) + __expf(ldsel(b_ls, t, f32f)) * ldsel(eps_b, t, f32f);
    if (t < H_DIM)
        gcnb_f[t] = ldsel(gcn_b, t, f32f);
}

// ---------------- ONE-PASS count + rank + ELL scatter (XCD-sharded) ---------
__global__ __launch_bounds__(256) void ell_scatter(const int* __restrict__ flags,
                                                   const int* __restrict__ ei,
                                                   int* __restrict__ cnt,
                                                   int* __restrict__ ell,
                                                   int2* __restrict__ ovf,
                                                   int* __restrict__ ocnt, int E) {
    const int shard = blockIdx.x & (NSHARD - 1);
    const int jb    = blockIdx.x >> 3;
    const int nb    = gridDim.x >> 3;
    const int lo = shard * SHARD_W;
    const int hi = lo + SHARD_W;                 // N divides evenly
    const int i64 = flags[1];
    for (long e = (long)jb * 256 + threadIdx.x; e < E; e += (long)nb * 256) {
        int d = i64 ? ei[2L * E + 2L * e] : ei[(long)E + e];
        if (d >= lo && d < hi) {
            int s = i64 ? ei[2L * e] : ei[e];
            int rk = atomicAdd(&cnt[d], 1);
            if (rk < MAXDEG) ell[(long)d * MAXDEG + rk] = s;
            else { int oi = atomicAdd(ocnt, 1); ovf[oi] = make_int2(s, d); }
        }
    }
}

// ------------------------------- h' = (x @ W) * rsqrt(deg+1) ----------------
// Round-15: LDS staging for W DELETED. W (64KB) is L2-resident on every XCD;
// B-fragments read directly from wtg with the same indexing the LDS held.
// Removes all barriers + ds traffic; waves free-run {x-load, B-loads, MFMA}.
// __launch_bounds__(256,4) caps VGPR at 128 -> 16 waves/CU resident.
__global__ __launch_bounds__(256, 4) void gemm_xw(const int* __restrict__ flags,
                                               const void* __restrict__ x_any,
                                               const ushort* __restrict__ wtg,
                                               const int* __restrict__ cnt,
                                               ushort* __restrict__ hout) {
    const int f32f = flags[0];

    const int tid  = threadIdx.x;
    const int lane = tid & 63;
    const int quad = lane >> 4;
    const int lm   = lane & 15;
    const int wave = tid >> 6;

    const int rbase = blockIdx.x * 128 + wave * 32;
    int arow0 = rbase + lm;
    int arow1 = rbase + 16 + lm;
    if (arow0 >= N_NODES) arow0 = N_NODES - 1;    // clamp; store is guarded
    if (arow1 >= N_NODES) arow1 = N_NODES - 1;
    const float*  xrf0 = (const float*) x_any + (size_t)arow0 * F_IN;
    const float*  xrf1 = (const float*) x_any + (size_t)arow1 * F_IN;
    const ushort* xrb0 = (const ushort*)x_any + (size_t)arow0 * F_IN;
    const ushort* xrb1 = (const ushort*)x_any + (size_t)arow1 * F_IN;

    float4v acc0[8], acc1[8];
#pragma unroll
    for (int c = 0; c < 8; ++c) {
        acc0[c] = (float4v){0.f, 0.f, 0.f, 0.f};
        acc1[c] = (float4v){0.f, 0.f, 0.f, 0.f};
    }

#pragma unroll 1
    for (int hh = 0; hh < 2; ++hh) {
#pragma unroll
        for (int s = 0; s < 4; ++s) {
            int klocal = s * 32 + quad * 8;
            short8 afrag0, afrag1;
            if (f32f) {
                const float* p0 = xrf0 + hh * 128 + klocal;
                const float* p1 = xrf1 + hh * 128 + klocal;
                float4 u0 = *(const float4*)p0;
                float4 u1 = *(const float4*)(p0 + 4);
                float4 u2 = *(const float4*)p1;
                float4 u3 = *(const float4*)(p1 + 4);
                afrag0[0] = (short)f2b(u0.x); afrag0[1] = (short)f2b(u0.y);
                afrag0[2] = (short)f2b(u0.z); afrag0[3] = (short)f2b(u0.w);
                afrag0[4] = (short)f2b(u1.x); afrag0[5] = (short)f2b(u1.y);
                afrag0[6] = (short)f2b(u1.z); afrag0[7] = (short)f2b(u1.w);
                afrag1[0] = (short)f2b(u2.x); afrag1[1] = (short)f2b(u2.y);
                afrag1[2] = (short)f2b(u2.z); afrag1[3] = (short)f2b(u2.w);
                afrag1[4] = (short)f2b(u3.x); afrag1[5] = (short)f2b(u3.y);
                afrag1[6] = (short)f2b(u3.z); afrag1[7] = (short)f2b(u3.w);
            } else {
                afrag0 = *(const short8*)(xrb0 + hh * 128 + klocal);
                afrag1 = *(const short8*)(xrb1 + hh * 128 + klocal);
            }
#pragma unroll
            for (int c = 0; c < 8; ++c) {
                int colr = c * 16 + lm;
                short8 bfrag = *(const short8*)(wtg + colr * F_IN + hh * 128 + klocal);
                acc0[c] = __builtin_amdgcn_mfma_f32_16x16x32_bf16(afrag0, bfrag, acc0[c], 0, 0, 0);
                acc1[c] = __builtin_amdgcn_mfma_f32_16x16x32_bf16(afrag1, bfrag, acc1[c], 0, 0, 0);
            }
        }
    }
    // D[row=quad*4+r][col=lane&15]; scale rows by rsqrt(deg+1) before rounding
    float dv0[4], dv1[4];
#pragma unroll
    for (int r = 0; r < 4; ++r) {
        int n0 = rbase + quad * 4 + r;
        int n1 = rbase + 16 + quad * 4 + r;
        dv0[r] = (n0 < N_NODES) ? rsqrtf((float)(cnt[n0] + 1)) : 0.f;
        dv1[r] = (n1 < N_NODES) ? rsqrtf((float)(cnt[n1] + 1)) : 0.f;
    }
#pragma unroll
    for (int c = 0; c < 8; ++c) {
        int col = c * 16 + lm;
#pragma unroll
        for (int r = 0; r < 4; ++r) {
            int n0 = rbase + quad * 4 + r;
            int n1 = rbase + 16 + quad * 4 + r;
            if (n0 < N_NODES) hout[(size_t)n0 * H_DIM + col] = f2b(acc0[c][r] * dv0[r]);
            if (n1 < N_NODES) hout[(size_t)n1 * H_DIM + col] = f2b(acc1[c][r] * dv1[r]);
        }
    }
}

// ------- FUSED: ELL gather + bias/relu -> LDS -> bayes linear + lsm ---------
// Round-13 form restored (round-14's per-batch predication broke load issue:
// masking must stay confined to the single tail batch, via wk=0 fma).
__global__ __launch_bounds__(256) void gather_final(const int* __restrict__ flags,
                                                    const int* __restrict__ cnt,
                                                    const int* __restrict__ ell,
                                                    const int2* __restrict__ ovf,
                                                    const int* __restrict__ ocnt,
                                                    const ushort* __restrict__ hb,
                                                    const float* __restrict__ gcnb_f,
                                                    const ushort* __restrict__ whi,
                                                    const ushort* __restrict__ wlo,
                                                    const float* __restrict__ bias16,
                                                    void* __restrict__ out) {
    __shared__ __align__(16) ushort alds[16][136];   // 4352 B, pad 8
    const int f32f = flags[0];
    const int lane = threadIdx.x & 63;
    const int wave = threadIdx.x >> 6;
    const int n0 = blockIdx.x * 16;                  // 16 | N_NODES

    // ---------------- gather phase: 4 nodes per wave, sequential ------------
    for (int r = 0; r < 4; ++r) {
        const int node = n0 + wave * 4 + r;
        const int degt = __builtin_amdgcn_readfirstlane(cnt[node]);
        const int deg  = degt < MAXDEG ? degt : MAXDEG;
        const int* pp = ell + (long)node * MAXDEG;

        float ax = 0.f, ay = 0.f;
        const int full = deg & ~15;
        for (int base = 0; base < full; base += 16) {
#pragma unroll
            for (int k = 0; k < 16; ++k) {
                int sk = pp[base + k];              // scalar 4B load (uniform)
                uint u = *((const uint*)(hb + (size_t)sk * H_DIM) + lane);
                ax += __uint_as_float(u << 16);
                ay += __uint_as_float(u & 0xFFFF0000u);
            }
        }
        {
            const int nb = deg - full;              // 0..15, uniform
#pragma unroll
            for (int k = 0; k < 16; ++k) {
                int   sk = 0;
                float wk = 0.f;
                if (k < nb) { sk = pp[full + k]; wk = 1.f; }
                uint u = *((const uint*)(hb + (size_t)sk * H_DIM) + lane);
                ax = fmaf(wk, __uint_as_float(u << 16),         ax);
                ay = fmaf(wk, __uint_as_float(u & 0xFFFF0000u), ay);
            }
        }
        if (degt > MAXDEG) {                        // rare: scan overflow list
            const int no = __builtin_amdgcn_readfirstlane(*ocnt);
            for (int j = 0; j < no; ++j) {
                int2 o = ovf[j];
                if (o.y == node) {
                    uint u = *((const uint*)(hb + (size_t)o.x * H_DIM) + lane);
                    ax += __uint_as_float(u << 16);
                    ay += __uint_as_float(u & 0xFFFF0000u);
                }
            }
        }

        const float dd = rsqrtf((float)(degt + 1));
        uint us = *((const uint*)(hb + (size_t)node * H_DIM) + lane); // h'[node]
        float2 gb = *(const float2*)(gcnb_f + 2 * lane);
        ax = (ax + __uint_as_float(us << 16))         * dd + gb.x;
        ay = (ay + __uint_as_float(us & 0xFFFF0000u)) * dd + gb.y;
        ax = fmaxf(ax, 0.f);
        ay = fmaxf(ay, 0.f);
        uint pack = (uint)f2b(ax) | ((uint)f2b(ay) << 16);
        *((uint*)&alds[wave * 4 + r][2 * lane]) = pack;
    }
    __syncthreads();
    if (wave != 0) return;

    // ---------------- final phase (wave 0): logits + log_softmax ------------
    const int lm = lane & 15, quad = lane >> 4;
    const ushort* bh = whi + lm * H_DIM + quad * 8;
    const ushort* bl = wlo + lm * H_DIM + quad * 8;

    float4v acc = (float4v){0.f, 0.f, 0.f, 0.f};
#pragma unroll
    for (int s = 0; s < 4; ++s) {
        short8 af = *(const short8*)&alds[lm][quad * 8 + s * 32];
        short8 b0 = *(const short8*)(bh + s * 32);
        short8 b1 = *(const short8*)(bl + s * 32);
        acc = __builtin_amdgcn_mfma_f32_16x16x32_bf16(af, b0, acc, 0, 0, 0);
        acc = __builtin_amdgcn_mfma_f32_16x16x32_bf16(af, b1, acc, 0, 0, 0);
    }

    const float bias = bias16[lm];
    float p[4], m[4], ss[4];
#pragma unroll
    for (int r = 0; r < 4; ++r) { p[r] = acc[r] + bias; m[r] = p[r]; }
#pragma unroll
    for (int off = 1; off < 16; off <<= 1)
#pragma unroll
        for (int r = 0; r < 4; ++r) m[r] = fmaxf(m[r], __shfl_xor(m[r], off, 64));
#pragma unroll
    for (int r = 0; r < 4; ++r) ss[r] = __expf(p[r] - m[r]);
#pragma unroll
    for (int off = 1; off < 16; off <<= 1)
#pragma unroll
        for (int r = 0; r < 4; ++r) ss[r] += __shfl_xor(ss[r], off, 64);

    if (f32f) {
        float* op = (float*)out;
#pragma unroll
        for (int r = 0; r < 4; ++r)
            op[(size_t)(n0 + quad * 4 + r) * C_CLS + lm] = p[r] - m[r] - __logf(ss[r]);
    } else {
        ushort* op = (ushort*)out;
#pragma unroll
        for (int r = 0; r < 4; ++r)
            op[(size_t)(n0 + quad * 4 + r) * C_CLS + lm] = f2b(p[r] - m[r] - __logf(ss[r]));
    }
}

// ---------------------------------------------------------------------------
extern "C" void kernel_launch(void* const* d_in, const int* in_sizes, int n_in,
                              void* d_out, int out_size, void* d_ws, size_t ws_size,
                              hipStream_t stream) {
    const int E = in_sizes[1] / 2;

    char* wp = (char*)d_ws;
    auto alloc = [&](size_t bytes) -> char* {
        char* p = wp; wp += (bytes + 511) & ~(size_t)511; return p;
    };
    int*    flags  = (int*)   alloc(64);
    ushort* hb     = (ushort*)alloc((size_t)N_NODES * H_DIM * 2);   // bf16 h*dis
    int*    cnt    = (int*)   alloc((size_t)N_NODES * 4);
    int*    ell    = (int*)   alloc((size_t)N_NODES * MAXDEG * 4);  // 25.6 MB
    int2*   ovf    = (int2*)  alloc((size_t)E * 8);                 // overflow (rare)
    int*    ocnt   = (int*)   alloc(64);
    ushort* wtg    = (ushort*)alloc((size_t)H_DIM * F_IN * 2);      // W^T bf16
    ushort* whi    = (ushort*)alloc((size_t)C_CLS * H_DIM * 2);
    ushort* wlo    = (ushort*)alloc((size_t)C_CLS * H_DIM * 2);
    float*  bias16 = (float*) alloc((size_t)C_CLS * 4);
    float*  gcnb_f = (float*) alloc((size_t)H_DIM * 4);

    sniff<<<1, 64, 0, stream>>>((const ushort*)d_in[0], (const int*)d_in[1], flags);
    prep_params<<<H_DIM + 1 + ZB, 256, 0, stream>>>(flags, d_in[2], wtg,
                                  d_in[4], d_in[5], d_in[8],
                                  d_in[6], d_in[7], d_in[9], d_in[3],
                                  whi, wlo, bias16, gcnb_f, cnt, ocnt);
    ell_scatter<<<2048, 256, 0, stream>>>(flags, (const int*)d_in[1], cnt, ell, ovf, ocnt, E);
    gemm_xw<<<(N_NODES + 127) / 128, 256, 0, stream>>>(flags, d_in[0], wtg, cnt, hb);
    gather_final<<<N_NODES / 16, 256, 0, stream>>>(flags, cnt, ell, ovf, ocnt, hb,
                                                   gcnb_f, whi, wlo, bias16, (void*)d_out);
}